// Round 1
// 435.117 us; speedup vs baseline: 1.0594x; 1.0594x over previous
//
#include <hip/hip_runtime.h>
#include <hip/hip_bf16.h>
#include <math.h>

#define TDIM 16384
#define DDIM 1024
#define CDIM 256
#define KDIM 8192
#define KSPLIT 8

typedef unsigned short u16;
typedef __attribute__((ext_vector_type(8))) short bf16x8;
typedef __attribute__((ext_vector_type(8))) unsigned short us8;
typedef __attribute__((ext_vector_type(4))) float floatx4;

// ---- workspace layout (float offsets) ----
static const size_t OFF_WINH  = 0;                                     // 256x1024 u16
static const size_t OFF_WINL  = OFF_WINH  + (size_t)CDIM * DDIM / 2;
static const size_t OFF_WOUTH = OFF_WINL  + (size_t)CDIM * DDIM / 2;   // 1024x256 u16
static const size_t OFF_WOUTL = OFF_WOUTH + (size_t)DDIM * CDIM / 2;
static const size_t OFF_CBH   = OFF_WOUTL + (size_t)DDIM * CDIM / 2;   // 8192x256 u16
static const size_t OFF_CBL   = OFF_CBH   + (size_t)KDIM * CDIM / 2;
static const size_t OFF_C2    = OFF_CBL   + (size_t)KDIM * CDIM / 2;   // 8192 f32
static const size_t OFF_ZTH   = OFF_C2    + (size_t)KDIM;              // 16384x1024 u16 [t][d]
static const size_t OFF_ZTL   = OFF_ZTH   + (size_t)TDIM * DDIM / 2;
static const size_t OFF_ZE    = OFF_ZTL   + (size_t)TDIM * DDIM / 2;   // 256x16384 f32
static const size_t OFF_PV    = OFF_ZE    + (size_t)CDIM * TDIM;       // 8x16384 f32
static const size_t OFF_PI    = OFF_PV    + (size_t)KSPLIT * TDIM;     // 8x16384 i32
static const size_t OFF_IDX   = OFF_PI    + (size_t)KSPLIT * TDIM;     // 16384 i32
// eth/etl [t][c] alias ZTH (zth/ztl dead after in_proj gemm);
// zqh/zql alias the same region again (eth/etl dead after dist_mfma).
static const size_t OFF_ETH   = OFF_ZTH;
static const size_t OFF_ETL   = OFF_ZTH + (size_t)TDIM * CDIM / 2;

static __device__ __forceinline__ u16 f2bf(float x) {
  __hip_bfloat16 h = __float2bfloat16(x);
  return *(u16*)&h;
}
static __device__ __forceinline__ float bf2f(u16 u) {
  __hip_bfloat16 h; *(u16*)&h = u;
  return __bfloat162float(h);
}

// ---------------------------------------------------------------------------
// Row-wise L2 normalize -> bf16 hi/lo split. Optional g, clip, c2.
// ---------------------------------------------------------------------------
__global__ __launch_bounds__(256) void rownorm_split(
    const float* __restrict__ v, const float* __restrict__ g,
    u16* __restrict__ hi, u16* __restrict__ lo, float* __restrict__ c2,
    int ncols, int clip) {
  __shared__ float red[256];
  int row = blockIdx.x;
  const float* vr = v + (size_t)row * ncols;
  float s = 0.f;
  for (int j = threadIdx.x; j < ncols; j += 256) { float x = vr[j]; s += x * x; }
  red[threadIdx.x] = s;
  __syncthreads();
  for (int off = 128; off > 0; off >>= 1) {
    if (threadIdx.x < off) red[threadIdx.x] += red[threadIdx.x + off];
    __syncthreads();
  }
  float norm = sqrtf(red[0]);
  if (clip) norm = fmaxf(norm, 1e-12f);
  float scale = (g ? g[row] : 1.0f) / norm;
  float s2 = 0.f;
  for (int j = threadIdx.x; j < ncols; j += 256) {
    float y = vr[j] * scale;
    u16 hh = f2bf(y);
    u16 ll = f2bf(y - bf2f(hh));
    hi[(size_t)row * ncols + j] = hh;
    lo[(size_t)row * ncols + j] = ll;
    s2 += y * y;
  }
  if (c2) {
    __syncthreads();
    red[threadIdx.x] = s2;
    __syncthreads();
    for (int off = 128; off > 0; off >>= 1) {
      if (threadIdx.x < off) red[threadIdx.x] += red[threadIdx.x + off];
      __syncthreads();
    }
    if (threadIdx.x == 0) c2[row] = red[0];
  }
}

// ---------------------------------------------------------------------------
// z [d][t] fp32 -> zth/ztl [t][d] bf16 hi/lo (LDS 64x64 tile transpose)
// ---------------------------------------------------------------------------
__global__ __launch_bounds__(256) void transpose_split_z(
    const float* __restrict__ z, u16* __restrict__ zth, u16* __restrict__ ztl) {
  __shared__ float tile[64][65];
  int t0 = blockIdx.x * 64, d0 = blockIdx.y * 64;
  int tl = threadIdx.x & 63, grp = threadIdx.x >> 6;
#pragma unroll
  for (int r = 0; r < 16; r++) {
    int d = grp * 16 + r;
    tile[d][tl] = z[(size_t)(d0 + d) * TDIM + t0 + tl];
  }
  __syncthreads();
#pragma unroll
  for (int r = 0; r < 16; r++) {
    int t = grp * 16 + r;
    float x = tile[tl][t];
    u16 h = f2bf(x);
    u16 l = f2bf(x - bf2f(h));
    zth[(size_t)(t0 + t) * DDIM + d0 + tl] = h;
    ztl[(size_t)(t0 + t) * DDIM + d0 + tl] = l;
  }
}

// ---------------------------------------------------------------------------
// in_proj split-bf16 MFMA GEMM, BN=64: C[m][t] = A[m]·B[t] + bias[m]
// ---------------------------------------------------------------------------
__global__ __launch_bounds__(256) void gemm_mfma_in(
    const u16* __restrict__ ah_g, const u16* __restrict__ al_g,
    const u16* __restrict__ bh_g, const u16* __restrict__ bl_g,
    const float* __restrict__ bias, float* __restrict__ C, int K) {
  __shared__ u16 Ah[128 * 32], Al[128 * 32];
  __shared__ u16 Bh[64 * 32],  Bl[64 * 32];
  int tid = threadIdx.x;
  int n0 = blockIdx.x * 64;      // t
  int m0 = blockIdx.y * 128;     // output rows
  int lane = tid & 63, wid = tid >> 6;
  int wr = wid >> 1, wc = wid & 1;
  int q = lane >> 4, mm = lane & 15;
  int h = tid & 1;
  int sr = ((tid >> 1) ^ (h << 2)) & 127;
  int ssw = (sr ^ (sr >> 2)) & 3;
  int o0 = sr * 32 + ((((h << 1))     ^ ssw) << 3);
  int o1 = sr * 32 + ((((h << 1) | 1) ^ ssw) << 3);
  int gcol = h * 16;
  // B staging (64 rows): threads tid<128 cover 64 rows x 2 halves
  int sb = ((tid >> 1) ^ (h << 2)) & 63;
  int ssb = (sb ^ (sb >> 2)) & 3;
  int p0 = sb * 32 + ((((h << 1))     ^ ssb) << 3);
  int p1 = sb * 32 + ((((h << 1) | 1) ^ ssb) << 3);
  int sm = (mm ^ (mm >> 2)) & 3;
  int cq = (q ^ sm) << 3;

  const floatx4 z4 = {0.f, 0.f, 0.f, 0.f};
  floatx4 acc[4][2];
#pragma unroll
  for (int i = 0; i < 4; i++)
#pragma unroll
    for (int j = 0; j < 2; j++) acc[i][j] = z4;

  for (int c0 = 0; c0 < K; c0 += 32) {
    const size_t ga = (size_t)(m0 + sr) * K + c0 + gcol;
    us8 a_h0 = *(const us8*)&ah_g[ga];
    us8 a_h1 = *(const us8*)&ah_g[ga + 8];
    us8 a_l0 = *(const us8*)&al_g[ga];
    us8 a_l1 = *(const us8*)&al_g[ga + 8];
    us8 b_h0, b_h1, b_l0, b_l1;
    if (tid < 128) {
      const size_t gb = (size_t)(n0 + sb) * K + c0 + gcol;
      b_h0 = *(const us8*)&bh_g[gb];
      b_h1 = *(const us8*)&bh_g[gb + 8];
      b_l0 = *(const us8*)&bl_g[gb];
      b_l1 = *(const us8*)&bl_g[gb + 8];
    }
    __syncthreads();
    *(us8*)&Ah[o0] = a_h0; *(us8*)&Ah[o1] = a_h1;
    *(us8*)&Al[o0] = a_l0; *(us8*)&Al[o1] = a_l1;
    if (tid < 128) {
      *(us8*)&Bh[p0] = b_h0; *(us8*)&Bh[p1] = b_h1;
      *(us8*)&Bl[p0] = b_l0; *(us8*)&Bl[p1] = b_l1;
    }
    __syncthreads();

    bf16x8 fa[4], fb[2];
#pragma unroll
    for (int i = 0; i < 4; i++)
      fa[i] = *(const bf16x8*)&Ah[(wr * 64 + i * 16 + mm) * 32 + cq];
#pragma unroll
    for (int j = 0; j < 2; j++)
      fb[j] = *(const bf16x8*)&Bh[(wc * 32 + j * 16 + mm) * 32 + cq];
#pragma unroll
    for (int i = 0; i < 4; i++)
#pragma unroll
      for (int j = 0; j < 2; j++)
        acc[i][j] = __builtin_amdgcn_mfma_f32_16x16x32_bf16(fa[i], fb[j], acc[i][j], 0, 0, 0);
#pragma unroll
    for (int i = 0; i < 4; i++) {
      bf16x8 fl = *(const bf16x8*)&Al[(wr * 64 + i * 16 + mm) * 32 + cq];
#pragma unroll
      for (int j = 0; j < 2; j++)
        acc[i][j] = __builtin_amdgcn_mfma_f32_16x16x32_bf16(fl, fb[j], acc[i][j], 0, 0, 0);
    }
#pragma unroll
    for (int j = 0; j < 2; j++) {
      bf16x8 fl = *(const bf16x8*)&Bl[(wc * 32 + j * 16 + mm) * 32 + cq];
#pragma unroll
      for (int i = 0; i < 4; i++)
        acc[i][j] = __builtin_amdgcn_mfma_f32_16x16x32_bf16(fa[i], fl, acc[i][j], 0, 0, 0);
    }
  }

#pragma unroll
  for (int i = 0; i < 4; i++) {
#pragma unroll
    for (int r = 0; r < 4; r++) {
      int m_loc = wr * 64 + i * 16 + q * 4 + r;
      float bb = bias[m0 + m_loc];
      float* crow = &C[(size_t)(m0 + m_loc) * TDIM + n0 + wc * 32 + mm];
#pragma unroll
      for (int j = 0; j < 2; j++) crow[j * 16] = acc[i][j][r] + bb;
    }
  }
}

// ---------------------------------------------------------------------------
// out_proj split-bf16 MFMA GEMM + bias, BN=128 (R6/R7-verified).
// ---------------------------------------------------------------------------
__global__ __launch_bounds__(256) void gemm_mfma_bias(
    const u16* __restrict__ ah_g, const u16* __restrict__ al_g,
    const u16* __restrict__ bh_g, const u16* __restrict__ bl_g,
    const float* __restrict__ bias, float* __restrict__ C, int K) {
  __shared__ u16 Ah[128 * 32], Al[128 * 32];
  __shared__ u16 Bh[128 * 32], Bl[128 * 32];
  int tid = threadIdx.x;
  int n0 = blockIdx.x * 128;
  int m0 = blockIdx.y * 128;
  int lane = tid & 63, wid = tid >> 6;
  int wr = wid >> 1, wc = wid & 1;
  int q = lane >> 4, mm = lane & 15;
  int h = tid & 1;
  int sr = ((tid >> 1) ^ (h << 2)) & 127;
  int ssw = (sr ^ (sr >> 2)) & 3;
  int o0 = sr * 32 + ((((h << 1))     ^ ssw) << 3);
  int o1 = sr * 32 + ((((h << 1) | 1) ^ ssw) << 3);
  int gcol = h * 16;
  int sm = (mm ^ (mm >> 2)) & 3;
  int cq = (q ^ sm) << 3;

  const floatx4 z4 = {0.f, 0.f, 0.f, 0.f};
  floatx4 acc[4][4];
#pragma unroll
  for (int i = 0; i < 4; i++)
#pragma unroll
    for (int j = 0; j < 4; j++) acc[i][j] = z4;

  for (int c0 = 0; c0 < K; c0 += 32) {
    const size_t ga = (size_t)(m0 + sr) * K + c0 + gcol;
    const size_t gb = (size_t)(n0 + sr) * K + c0 + gcol;
    us8 a_h0 = *(const us8*)&ah_g[ga];
    us8 a_h1 = *(const us8*)&ah_g[ga + 8];
    us8 a_l0 = *(const us8*)&al_g[ga];
    us8 a_l1 = *(const us8*)&al_g[ga + 8];
    us8 b_h0 = *(const us8*)&bh_g[gb];
    us8 b_h1 = *(const us8*)&bh_g[gb + 8];
    us8 b_l0 = *(const us8*)&bl_g[gb];
    us8 b_l1 = *(const us8*)&bl_g[gb + 8];
    __syncthreads();
    *(us8*)&Ah[o0] = a_h0; *(us8*)&Ah[o1] = a_h1;
    *(us8*)&Al[o0] = a_l0; *(us8*)&Al[o1] = a_l1;
    *(us8*)&Bh[o0] = b_h0; *(us8*)&Bh[o1] = b_h1;
    *(us8*)&Bl[o0] = b_l0; *(us8*)&Bl[o1] = b_l1;
    __syncthreads();

    bf16x8 fa[4], fb[4];
#pragma unroll
    for (int i = 0; i < 4; i++)
      fa[i] = *(const bf16x8*)&Ah[(wr * 64 + i * 16 + mm) * 32 + cq];
#pragma unroll
    for (int j = 0; j < 4; j++)
      fb[j] = *(const bf16x8*)&Bh[(wc * 64 + j * 16 + mm) * 32 + cq];
#pragma unroll
    for (int i = 0; i < 4; i++)
#pragma unroll
      for (int j = 0; j < 4; j++)
        acc[i][j] = __builtin_amdgcn_mfma_f32_16x16x32_bf16(fa[i], fb[j], acc[i][j], 0, 0, 0);
#pragma unroll
    for (int i = 0; i < 4; i++) {
      bf16x8 fl = *(const bf16x8*)&Al[(wr * 64 + i * 16 + mm) * 32 + cq];
#pragma unroll
      for (int j = 0; j < 4; j++)
        acc[i][j] = __builtin_amdgcn_mfma_f32_16x16x32_bf16(fl, fb[j], acc[i][j], 0, 0, 0);
    }
#pragma unroll
    for (int j = 0; j < 4; j++) {
      bf16x8 fl = *(const bf16x8*)&Bl[(wc * 64 + j * 16 + mm) * 32 + cq];
#pragma unroll
      for (int i = 0; i < 4; i++)
        acc[i][j] = __builtin_amdgcn_mfma_f32_16x16x32_bf16(fa[i], fl, acc[i][j], 0, 0, 0);
    }
  }

#pragma unroll
  for (int i = 0; i < 4; i++) {
#pragma unroll
    for (int r = 0; r < 4; r++) {
      int m_loc = wr * 64 + i * 16 + q * 4 + r;
      float bb = bias[m0 + m_loc];
      float* crow = &C[(size_t)(m0 + m_loc) * TDIM + n0 + wc * 64 + mm];
#pragma unroll
      for (int j = 0; j < 4; j++) crow[j * 16] = acc[i][j][r] + bb;
    }
  }
}

// ---------------------------------------------------------------------------
// finish_ze: fused column-norm + transpose + bf16 split, 32-t tiles.
// ---------------------------------------------------------------------------
__global__ __launch_bounds__(256) void finish_ze(
    const float* __restrict__ ze, u16* __restrict__ eth, u16* __restrict__ etl) {
  __shared__ float tile[256][33];
  __shared__ float red[8][32];
  __shared__ float invs[32];
  int t0 = blockIdx.x * 32;
  int tl = threadIdx.x & 31, grp = threadIdx.x >> 5;
  float s = 0.f;
  for (int c = grp * 32; c < grp * 32 + 32; c++) {
    float v = ze[(size_t)c * TDIM + t0 + tl];
    tile[c][tl] = v;
    s += v * v;
  }
  red[grp][tl] = s;
  __syncthreads();
  if (grp == 0) {
    float tot = 0.f;
#pragma unroll
    for (int gg = 0; gg < 8; gg++) tot += red[gg][tl];
    invs[tl] = 1.0f / fmaxf(sqrtf(tot), 1e-12f);
  }
  __syncthreads();
#pragma unroll
  for (int r = 0; r < 4; r++) {
    int t = grp * 4 + r;
    float iv = invs[t];
#pragma unroll
    for (int cc = 0; cc < 8; cc++) {
      int cd = cc * 32 + tl;
      float x = tile[cd][t] * iv;
      u16 hh = f2bf(x);
      u16 ll = f2bf(x - bf2f(hh));
      eth[(size_t)(t0 + t) * CDIM + cd] = hh;
      etl[(size_t)(t0 + t) * CDIM + cd] = ll;
    }
  }
}

// ---------------------------------------------------------------------------
// dist + argmin via split-bf16 MFMA — RESTRUCTURED (R8):
// 512 threads, 1 block/CU, block tile 256k x 128t per k-step (4 k-steps).
//   - Bh (enc hi, [128t][256c]) persistent in LDS, staged ONCE per block
//     with 5-bit XOR swizzle (row stride 512B -> full 32-bank spread).
//   - A hi/lo (codebook) + Bl streamed per 32-col chunk, DOUBLE-BUFFERED:
//     issue global loads for chunk n+1 early, ds_write after MFMAs,
//     ONE barrier per chunk (vs 2 before; 32 barriers/block vs 128).
//   - wave tile 64k x 64t -> acc[4][4]: 48 MFMA per chunk per wave vs
//     16 ds_read_b128 (LDS-pipe demand ~72% of MFMA-pipe demand).
// Per-(t,k) accumulation sequence (hihi, lo*bh, ah*bl per c0, c0 asc, fp32
// MFMA acc) identical to previous verified kernel -> dist values bit-equal
// -> indices bit-equal. Tie rules (strict <, tie -> lower k) unchanged.
// LDS 148KB -> 1 block/CU, 8 waves (2/SIMD).
// ---------------------------------------------------------------------------
__global__ __launch_bounds__(512, 2) void dist_mfma(
    const u16* __restrict__ eth, const u16* __restrict__ etl,
    const u16* __restrict__ cbh, const u16* __restrict__ cbl,
    const float* __restrict__ c2, float* __restrict__ pv, int* __restrict__ pi) {
  __shared__ u16 Bh[128 * 256];        // 64 KB, persistent enc-hi
  __shared__ u16 Ah[2][256 * 32];      // 32 KB, codebook-hi dbuf
  __shared__ u16 Al[2][256 * 32];      // 32 KB, codebook-lo dbuf
  __shared__ u16 Bls[2][128 * 32];     // 16 KB, enc-lo dbuf
  __shared__ float mv[4][128];
  __shared__ int   mi[4][128];

  int tid = threadIdx.x;
  int t0 = blockIdx.x * 128;
  int kbeg = blockIdx.y * (KDIM / KSPLIT);
  int lane = tid & 63, wid = tid >> 6;
  int wk = wid >> 1, wt = wid & 1;       // 4 waves along k, 2 along t
  int q = lane >> 4, mm = lane & 15;
  int sm2 = (mm ^ (mm >> 2)) & 3;
  int cq2 = (q ^ sm2) << 3;
  int sm5 = sm2 | (((mm >> 1) & 1) << 2);

  // per-thread staging constants (granule = 16B = 8 u16)
  int rA = tid >> 2;                       // 0..127
  int gA = tid & 3;
  int sswA = (rA ^ (rA >> 2)) & 3;
  int colA = (gA ^ sswA) << 3;             // swizzled source column (u16)
  int ldsA = rA * 32 + (gA << 3);          // linear LDS position (u16)

  // ---- persistent Bh staging (once): LDS pos p5 holds global granule p5^f5
  for (int it = 0; it < 8; ++it) {
    int gi = it * 512 + tid;               // 0..4095
    int r = gi >> 5, p5 = gi & 31;
    int f5 = ((r ^ (r >> 2)) & 3) | (((r >> 1) & 1) << 2);
    us8 v = *(const us8*)&eth[(size_t)(t0 + r) * CDIM + ((p5 ^ f5) << 3)];
    *(us8*)&Bh[r * 256 + (p5 << 3)] = v;
  }

  // ---- prologue: stage chunk 0 (k-step 0, c0=0) into buf 0
  {
    const size_t ga = (size_t)(kbeg + rA) * CDIM + colA;
    us8 ah0 = *(const us8*)&cbh[ga];
    us8 ah1 = *(const us8*)&cbh[ga + (size_t)128 * CDIM];
    us8 al0 = *(const us8*)&cbl[ga];
    us8 al1 = *(const us8*)&cbl[ga + (size_t)128 * CDIM];
    us8 bl0 = *(const us8*)&etl[(size_t)(t0 + rA) * CDIM + colA];
    *(us8*)&Ah[0][ldsA] = ah0; *(us8*)&Ah[0][ldsA + 4096] = ah1;
    *(us8*)&Al[0][ldsA] = al0; *(us8*)&Al[0][ldsA + 4096] = al1;
    *(us8*)&Bls[0][ldsA] = bl0;
  }
  __syncthreads();

  float rbv[4]; int rbi[4];
#pragma unroll
  for (int j = 0; j < 4; j++) { rbv[j] = INFINITY; rbi[j] = 0x7fffffff; }

  const floatx4 z4 = {0.f, 0.f, 0.f, 0.f};
  floatx4 acc[4][4];
#pragma unroll
  for (int i = 0; i < 4; i++)
#pragma unroll
    for (int j = 0; j < 4; j++) acc[i][j] = z4;

  int cur = 0;
  for (int n = 0; n < 32; ++n) {           // 4 k-steps x 8 c0-chunks
    int cc = n & 7;

    // issue-early: global loads for chunk n+1 (land during MFMAs below)
    us8 ah0, ah1, al0, al1, bl0;
    if (n < 31) {
      int n1 = n + 1;
      int k0n = kbeg + (n1 >> 3) * 256;
      int c0n = (n1 & 7) * 32;
      const size_t ga = (size_t)(k0n + rA) * CDIM + c0n + colA;
      ah0 = *(const us8*)&cbh[ga];
      ah1 = *(const us8*)&cbh[ga + (size_t)128 * CDIM];
      al0 = *(const us8*)&cbl[ga];
      al1 = *(const us8*)&cbl[ga + (size_t)128 * CDIM];
      bl0 = *(const us8*)&etl[(size_t)(t0 + rA) * CDIM + c0n + colA];
    }

    // compute chunk n from buf[cur] (+ persistent Bh)
    bf16x8 fah[4], fbh[4];
#pragma unroll
    for (int i = 0; i < 4; i++)
      fah[i] = *(const bf16x8*)&Ah[cur][(wk * 64 + i * 16 + mm) * 32 + cq2];
#pragma unroll
    for (int j = 0; j < 4; j++)
      fbh[j] = *(const bf16x8*)&Bh[(wt * 64 + j * 16 + mm) * 256 +
                                   ((((cc << 2) | q) ^ sm5) << 3)];
#pragma unroll
    for (int i = 0; i < 4; i++)
#pragma unroll
      for (int j = 0; j < 4; j++)
        acc[i][j] = __builtin_amdgcn_mfma_f32_16x16x32_bf16(fah[i], fbh[j], acc[i][j], 0, 0, 0);
#pragma unroll
    for (int i = 0; i < 4; i++) {
      bf16x8 fl = *(const bf16x8*)&Al[cur][(wk * 64 + i * 16 + mm) * 32 + cq2];
#pragma unroll
      for (int j = 0; j < 4; j++)
        acc[i][j] = __builtin_amdgcn_mfma_f32_16x16x32_bf16(fl, fbh[j], acc[i][j], 0, 0, 0);
    }
#pragma unroll
    for (int j = 0; j < 4; j++) {
      bf16x8 fl = *(const bf16x8*)&Bls[cur][(wt * 64 + j * 16 + mm) * 32 + cq2];
#pragma unroll
      for (int i = 0; i < 4; i++)
        acc[i][j] = __builtin_amdgcn_mfma_f32_16x16x32_bf16(fah[i], fl, acc[i][j], 0, 0, 0);
    }

    // write-late: commit chunk n+1 into the other buffer
    if (n < 31) {
      int nb = cur ^ 1;
      *(us8*)&Ah[nb][ldsA] = ah0; *(us8*)&Ah[nb][ldsA + 4096] = ah1;
      *(us8*)&Al[nb][ldsA] = al0; *(us8*)&Al[nb][ldsA + 4096] = al1;
      *(us8*)&Bls[nb][ldsA] = bl0;
    }
    __syncthreads();
    cur ^= 1;

    // k-step epilogue: fold acc into running argmin, reset acc
    if (cc == 7) {
      int k0 = kbeg + (n >> 3) * 256;
#pragma unroll
      for (int i = 0; i < 4; i++) {
#pragma unroll
        for (int r4 = 0; r4 < 4; r4++) {
          int kg = k0 + wk * 64 + i * 16 + q * 4 + r4;
          float c2v = c2[kg];
#pragma unroll
          for (int j = 0; j < 4; j++) {
            float s = c2v - 2.0f * acc[i][j][r4];
            if (s < rbv[j]) { rbv[j] = s; rbi[j] = kg; }
          }
        }
      }
#pragma unroll
      for (int i = 0; i < 4; i++)
#pragma unroll
        for (int j = 0; j < 4; j++) acc[i][j] = z4;
    }
  }

  // cross-lane reduce over q (lanes 16/32 apart hold same t)
#pragma unroll
  for (int j = 0; j < 4; j++) {
    float v = rbv[j]; int ii = rbi[j];
    float ov = __shfl_xor(v, 16, 64); int oi = __shfl_xor(ii, 16, 64);
    if (ov < v || (ov == v && oi < ii)) { v = ov; ii = oi; }
    ov = __shfl_xor(v, 32, 64); oi = __shfl_xor(ii, 32, 64);
    if (ov < v || (ov == v && oi < ii)) { v = ov; ii = oi; }
    rbv[j] = v; rbi[j] = ii;
  }
  if (q == 0) {
#pragma unroll
    for (int j = 0; j < 4; j++) {
      mv[wk][wt * 64 + j * 16 + mm] = rbv[j];
      mi[wk][wt * 64 + j * 16 + mm] = rbi[j];
    }
  }
  __syncthreads();
  if (tid < 128) {
    float v0 = mv[0][tid]; int i0 = mi[0][tid];
#pragma unroll
    for (int w = 1; w < 4; w++) {
      float v1 = mv[w][tid]; int i1 = mi[w][tid];
      if (v1 < v0 || (v1 == v0 && i1 < i0)) { v0 = v1; i0 = i1; }
    }
    pv[(size_t)blockIdx.y * TDIM + t0 + tid] = v0;
    pi[(size_t)blockIdx.y * TDIM + t0 + tid] = i0;
  }
}

// ---------------------------------------------------------------------------
// merge k-splits; emit int idx (for gather) and float idx (output 1)
// ---------------------------------------------------------------------------
__global__ __launch_bounds__(256) void merge_argmin(
    const float* __restrict__ pv, const int* __restrict__ pi,
    int* __restrict__ idx, float* __restrict__ idxf) {
  int t = blockIdx.x * 256 + threadIdx.x;
  float bv = INFINITY; int bi = 0x7fffffff;
  for (int s = 0; s < KSPLIT; s++) {
    float v = pv[(size_t)s * TDIM + t];
    int ii = pi[(size_t)s * TDIM + t];
    if (v < bv || (v == bv && ii < bi)) { bv = v; bi = ii; }
  }
  idx[t] = bi;
  idxf[t] = (float)bi;
}

// ---------------------------------------------------------------------------
// gather: zqT[t][c] = split(cb[idx[t]][c]); 4 t per block, float4 loads.
// ---------------------------------------------------------------------------
__global__ __launch_bounds__(256) void gather_split(
    const int* __restrict__ idx, const float* __restrict__ cb,
    u16* __restrict__ zqh, u16* __restrict__ zql) {
  int t = blockIdx.x * 4 + (threadIdx.x >> 6);
  int c4 = (threadIdx.x & 63) * 4;
  int k = idx[t];
  float4 x = *(const float4*)&cb[(size_t)k * CDIM + c4];
  u16 h0 = f2bf(x.x), h1 = f2bf(x.y), h2 = f2bf(x.z), h3 = f2bf(x.w);
  u16 l0 = f2bf(x.x - bf2f(h0)), l1 = f2bf(x.y - bf2f(h1));
  u16 l2 = f2bf(x.z - bf2f(h2)), l3 = f2bf(x.w - bf2f(h3));
  ushort4 hv = {h0, h1, h2, h3}, lv = {l0, l1, l2, l3};
  *(ushort4*)&zqh[(size_t)t * CDIM + c4] = hv;
  *(ushort4*)&zql[(size_t)t * CDIM + c4] = lv;
}

extern "C" void kernel_launch(void* const* d_in, const int* in_sizes, int n_in,
                              void* d_out, int out_size, void* d_ws, size_t ws_size,
                              hipStream_t stream) {
  const float* z     = (const float*)d_in[0];
  const float* in_v  = (const float*)d_in[1];
  const float* in_g  = (const float*)d_in[2];
  const float* in_b  = (const float*)d_in[3];
  const float* out_v = (const float*)d_in[4];
  const float* out_g = (const float*)d_in[5];
  const float* out_b = (const float*)d_in[6];
  const float* cb    = (const float*)d_in[7];

  float* ws    = (float*)d_ws;
  u16*   winh  = (u16*)(ws + OFF_WINH);
  u16*   winl  = (u16*)(ws + OFF_WINL);
  u16*   wouth = (u16*)(ws + OFF_WOUTH);
  u16*   woutl = (u16*)(ws + OFF_WOUTL);
  u16*   cbh   = (u16*)(ws + OFF_CBH);
  u16*   cbl   = (u16*)(ws + OFF_CBL);
  float* c2    = ws + OFF_C2;
  u16*   zth   = (u16*)(ws + OFF_ZTH);
  u16*   ztl   = (u16*)(ws + OFF_ZTL);
  float* z_e   = ws + OFF_ZE;
  float* pv    = ws + OFF_PV;
  int*   pi    = (int*)(ws + OFF_PI);
  int*   idxw  = (int*)(ws + OFF_IDX);
  u16*   eth   = (u16*)(ws + OFF_ETH);   // aliases zth (dead after in_proj)
  u16*   etl   = (u16*)(ws + OFF_ETL);
  u16*   zqh   = eth;                    // aliases eth (dead after dist)
  u16*   zql   = etl;

  float* outp = (float*)d_out;                 // (1024 x 16384) fp32
  float* idxf = outp + (size_t)DDIM * TDIM;    // indices as float32

  // weight prep: all weights emitted directly as split-bf16
  rownorm_split<<<CDIM, 256, 0, stream>>>(in_v, in_g, winh, winl, nullptr, DDIM, 0);
  rownorm_split<<<DDIM, 256, 0, stream>>>(out_v, out_g, wouth, woutl, nullptr, CDIM, 0);
  rownorm_split<<<KDIM, 256, 0, stream>>>(cb, nullptr, cbh, cbl, c2, CDIM, 1);

  // z -> zT split (for in_proj B operand)
  transpose_split_z<<<dim3(TDIM / 64, DDIM / 64), 256, 0, stream>>>(z, zth, ztl);

  // z_e = W_in @ z + in_b  (split-bf16 MFMA, BN=64, K=1024)
  gemm_mfma_in<<<dim3(TDIM / 64, CDIM / 128), 256, 0, stream>>>(
      winh, winl, zth, ztl, in_b, z_e, DDIM);

  // fused colnorm + transpose + split -> eth/etl [t][c]
  finish_ze<<<TDIM / 32, 256, 0, stream>>>(z_e, eth, etl);

  // nearest-codebook argmin (k-split x8), restructured B-persistent dbuf
  dist_mfma<<<dim3(TDIM / 128, KSPLIT), 512, 0, stream>>>(eth, etl, cbh, cbl, c2, pv, pi);
  merge_argmin<<<TDIM / 256, 256, 0, stream>>>(pv, pi, idxw, idxf);

  // zq = cb[idx] -> split [t][c]
  gather_split<<<TDIM / 4, 256, 0, stream>>>(idxw, cb, zqh, zql);

  // out = W_out @ z_q + out_b  (split-bf16 MFMA, K=256)
  gemm_mfma_bias<<<dim3(TDIM / 128, DDIM / 128), 256, 0, stream>>>(
      wouth, woutl, zqh, zql, out_b, outp, CDIM);
}